// Round 11
// baseline (2682.481 us; speedup 1.0000x reference)
//
#include <hip/hip_runtime.h>

// LightGCN: final = (x0 + x1 + x2 + x3) / 4, x_{l+1}[r] = sum_{e:row=r} x_l[col_e]*norm_e
// norm_e = rsqrt(deg[row_e]) * rsqrt(deg[col_e]), deg = clip(bincount(row),1)
// N = 150000 nodes, d = 64, E = 2.4M edges. Output fp32.
//
// R23: EDGE-PARALLEL pulls with LDS f32 accumulators; fine kernel DELETED.
// Insight: a bucket window holds ALL edges of its rows -> each pull block
// (one 128-row half-bucket) computes deg via LDS hist and accumulates
// edge-parallel (8-lane group per edge, 8 ds_add_f32 per lane into
// acc[128][65], pad 65 -> bank=(r+d)&31, ~2-way). No row-sort, no be[],
// no divergence, no dummy row. Staged-edge compaction via wave ballot
// (1 LDS atomic per wave -- R20 lesson: never per-thread on one counter).
// CSR = partition (R22 LDS-staged form) + tiny y0 kernel.
// x-tables stay 4096-B aligned (R15 lesson: misaligned rows = +122MB FETCH).

#define NUM_USERS 100000
#define NUM_ITEMS 50000
#define EMBED_DIM 64
#define N_NODES   150000
#define N_EDGES   2400000
#define N_BUCKETS 586       // 256 rows per bucket
#define BCAP      4608      // static per-bucket window (ints)
#define PART_BLOCKS 256
#define MAX_BLK_EDGES 9376  // ceil(600000/256)*4
#define NHB       1172      // half-buckets (128 rows each) = pull grid
#define SCAP      2816      // staged edges per half-bucket (mean 2048 + 17 sigma)

// ws layout (byte offsets), total 51,013,760 <= proven 51,033,344
// (old be/rsqd regions now dead space; offsets unchanged -> alignment kept):
#define OFF_BCNT  0         // int32 x 586 (zeroed per launch)
#define OFF_PS    1808256   // int32 x 586*4608 (128-aligned; ends 12,609,408)
#define OFF_XA    12611584  // bf16 x (N+1)*64 = 19,200,128  (4096-aligned)
#define OFF_XB    31813632  // bf16 x (N+1)*64               (4096-aligned)

__device__ __forceinline__ unsigned f2bf(float f) {  // RNE fp32 -> bf16 (as u16)
    unsigned u = __float_as_uint(f);
    return (u + 0x7fffu + ((u >> 16) & 1u)) >> 16;
}
__device__ __forceinline__ float bflo(unsigned u) { return __uint_as_float(u << 16); }
__device__ __forceinline__ float bfhi(unsigned u) { return __uint_as_float(u & 0xffff0000u); }

// Pass 1: partition into static bucket windows, LDS-staged for coalesced
// writes (R22 form). pack = (row&255)<<18 | col.
__global__ void partition_kernel(const int4* __restrict__ row4, const int4* __restrict__ col4,
                                 int* __restrict__ bcnt, unsigned* __restrict__ ps) {
    __shared__ int scanws[1024];                 // scan workspace (padded hist)
    __shared__ int lsize[N_BUCKETS];             // per-bucket count in this block
    __shared__ int lstart[N_BUCKETS + 1];        // exclusive starts in staged[]
    __shared__ int gbase[N_BUCKETS];             // reserved global bases
    __shared__ int lcur[N_BUCKETS];              // scatter cursors
    __shared__ unsigned staged[MAX_BLK_EDGES];   // bucket-sorted packed edges
    scanws[threadIdx.x] = 0;
    __syncthreads();
    const int total4 = N_EDGES / 4;
    int per4 = (total4 + gridDim.x - 1) / gridDim.x;
    int s4 = blockIdx.x * per4;
    int e4 = s4 + per4; if (e4 > total4) e4 = total4;
    const int cntE = (e4 - s4) * 4;
    // 1) histogram
    for (int i = s4 + (int)threadIdx.x; i < e4; i += (int)blockDim.x) {
        int4 r = row4[i];
        atomicAdd(&scanws[r.x >> 8], 1);
        atomicAdd(&scanws[r.y >> 8], 1);
        atomicAdd(&scanws[r.z >> 8], 1);
        atomicAdd(&scanws[r.w >> 8], 1);
    }
    __syncthreads();
    int myv = scanws[threadIdx.x];               // padded: 0 for t >= N_BUCKETS
    if (threadIdx.x < N_BUCKETS) lsize[threadIdx.x] = myv;
    __syncthreads();
    // 2) Hillis-Steele inclusive scan over 1024 (covers 586)
    for (int off = 1; off < 1024; off <<= 1) {
        int t = (threadIdx.x >= off) ? scanws[threadIdx.x - off] : 0;
        __syncthreads();
        scanws[threadIdx.x] += t;
        __syncthreads();
    }
    if (threadIdx.x < N_BUCKETS) {
        int incl = scanws[threadIdx.x];
        int st = incl - lsize[threadIdx.x];
        lstart[threadIdx.x] = st;
        lcur[threadIdx.x] = st;
        int c = lsize[threadIdx.x];
        gbase[threadIdx.x] = c ? (threadIdx.x * BCAP + atomicAdd(&bcnt[threadIdx.x], c)) : 0;
    }
    if (threadIdx.x == 0) lstart[N_BUCKETS] = cntE;
    __syncthreads();
    // 3) scatter into bucket-sorted LDS
    for (int i = s4 + (int)threadIdx.x; i < e4; i += (int)blockDim.x) {
        int4 r = row4[i];
        int4 c = col4[i];
        int pos;
        pos = atomicAdd(&lcur[r.x >> 8], 1); staged[pos] = ((unsigned)(r.x & 255) << 18) | (unsigned)c.x;
        pos = atomicAdd(&lcur[r.y >> 8], 1); staged[pos] = ((unsigned)(r.y & 255) << 18) | (unsigned)c.y;
        pos = atomicAdd(&lcur[r.z >> 8], 1); staged[pos] = ((unsigned)(r.z & 255) << 18) | (unsigned)c.z;
        pos = atomicAdd(&lcur[r.w >> 8], 1); staged[pos] = ((unsigned)(r.w & 255) << 18) | (unsigned)c.w;
    }
    __syncthreads();
    // 4) sequential writeback: consecutive i -> consecutive dest within runs
    for (int i = (int)threadIdx.x; i < cntE; i += (int)blockDim.x) {
        int lo = 0, hi = N_BUCKETS - 1;          // largest b with lstart[b] <= i
        while (lo < hi) {
            int mid = (lo + hi + 1) >> 1;
            if (lstart[mid] <= i) lo = mid; else hi = mid - 1;
        }
        ps[gbase[lo] + (i - lstart[lo])] = staged[i];
    }
}

// Pass 2: y0 rows. One block per 128-row half-bucket: LDS hist of its rows
// (bucket window holds ALL their edges) -> y0 = x0 * rsqrt(deg), streamed.
__global__ __launch_bounds__(512) void y0_kernel(const int* __restrict__ bcnt,
                                                 const int* __restrict__ ps,
                                                 const float4* __restrict__ user,
                                                 const float4* __restrict__ item,
                                                 uint2* __restrict__ yA) {
    __shared__ int hist[128];
    int hb = blockIdx.x, b = hb >> 1, half = hb & 1;
    int base = b * BCAP;
    int cnt = bcnt[b]; if (cnt > BCAP) cnt = BCAP;
    if (threadIdx.x < 128) hist[threadIdx.x] = 0;
    __syncthreads();
    for (int i = threadIdx.x; i < cnt; i += 512) {
        int p = ps[base + i];
        if (((p >> 25) & 1) == half) atomicAdd(&hist[(p >> 18) & 127], 1);
    }
    __syncthreads();
    for (int idx = threadIdx.x; idx < 2048; idx += 512) {   // 128 rows x 16 uint2
        int r = idx >> 4, w = idx & 15;
        int n = (hb << 7) + r;
        if (n < N_NODES) {
            int dg = hist[r];
            float d = (float)(dg < 1 ? 1 : dg);
            float rn = rsqrtf(d);
            const float4* src = (n < NUM_USERS) ? (user + (size_t)n * 16)
                                                : (item + (size_t)(n - NUM_USERS) * 16);
            float4 v = src[w];
            uint2 o;
            o.x = f2bf(v.x * rn) | (f2bf(v.y * rn) << 16);
            o.y = f2bf(v.z * rn) | (f2bf(v.w * rn) << 16);
            yA[(size_t)n * 16 + w] = o;
        }
    }
}

// Shared preamble for pull kernels: filter this half-bucket's edges into
// sedge[] (wave-ballot compaction, 1 LDS atomic per wave), build hist,
// zero acc, then edge-parallel accumulate: 8-lane group per edge, lane q
// owns dims [8q,8q+8); 8 ds_add_f32 into acc[r][d] (stride 65 -> bank
// (r+d)&31). Returns tot staged.
__device__ __forceinline__ int pull_accum(int hb, const int* __restrict__ bcnt,
                                          const int* __restrict__ ps,
                                          const uint4* __restrict__ xin,
                                          unsigned* sedge, int* hist, int* scnt,
                                          float* accs) {
    int b = hb >> 1, half = hb & 1;
    int base = b * BCAP;
    int cnt = bcnt[b]; if (cnt > BCAP) cnt = BCAP;
    if (threadIdx.x < 128) hist[threadIdx.x] = 0;
    if (threadIdx.x == 0) *scnt = 0;
    for (int idx = threadIdx.x; idx < 128 * 65; idx += 512) accs[idx] = 0.f;
    __syncthreads();
    int lane = threadIdx.x & 63;
    int iters = (cnt + 511) >> 9;
    for (int it = 0; it < iters; ++it) {
        int i = (it << 9) + (int)threadIdx.x;
        bool valid = i < cnt;
        int p = valid ? ps[base + i] : 0;
        bool match = valid && (((p >> 25) & 1) == half);
        unsigned long long m = __ballot(match);
        int off = 0;
        if (lane == 0 && m) off = atomicAdd(scnt, __popcll(m));
        off = __shfl(off, 0);
        if (match) {
            int pos = off + __popcll(m & ((1ull << lane) - 1ull));
            if (pos < SCAP) sedge[pos] = (unsigned)p;
            atomicAdd(&hist[(p >> 18) & 127], 1);
        }
    }
    __syncthreads();
    int tot = *scnt; if (tot > SCAP) tot = SCAP;
    int g = threadIdx.x >> 3, q = threadIdx.x & 7;       // 64 groups of 8
    for (int i = g; i < tot; i += 64) {
        unsigned p = sedge[i];                            // LDS broadcast in group
        int r = (int)((p >> 18) & 127);
        int c = (int)(p & 0x3FFFFu);
        uint4 X = xin[(size_t)c * 8 + q];                 // 8 lanes -> one 128B line
        float* ar = &accs[r * 65 + q * 8];
        atomicAdd(&ar[0], bflo(X.x)); atomicAdd(&ar[1], bfhi(X.x));
        atomicAdd(&ar[2], bflo(X.y)); atomicAdd(&ar[3], bfhi(X.y));
        atomicAdd(&ar[4], bflo(X.z)); atomicAdd(&ar[5], bfhi(X.z));
        atomicAdd(&ar[6], bflo(X.w)); atomicAdd(&ar[7], bfhi(X.w));
    }
    __syncthreads();
    return tot;
}

// Middle layers: y_{l+1}[n] = rsqrt(deg)^2 * acc  (bf16).
__global__ __launch_bounds__(512) void pull_kernel(const int* __restrict__ bcnt,
                                                   const int* __restrict__ ps,
                                                   const uint4* __restrict__ xin,
                                                   uint4* __restrict__ xout) {
    __shared__ unsigned sedge[SCAP];
    __shared__ int hist[128];
    __shared__ int scnt;
    __shared__ float accs[128 * 65];
    int hb = blockIdx.x;
    pull_accum(hb, bcnt, ps, xin, sedge, hist, &scnt, accs);
    // epilogue: 4 threads per row, each 16 dims = 2 uint4 words
    int r = threadIdx.x >> 2, part = threadIdx.x & 3;
    int n = (hb << 7) + r;
    if (n < N_NODES) {
        int dg = hist[r];
        float d = (float)(dg < 1 ? 1 : dg);
        float rn = rsqrtf(d);
        float s2 = rn * rn;
        const float* ar = &accs[r * 65 + part * 16];
        uint4 p0, p1;
        p0.x = f2bf(ar[0] * s2)  | (f2bf(ar[1] * s2)  << 16);
        p0.y = f2bf(ar[2] * s2)  | (f2bf(ar[3] * s2)  << 16);
        p0.z = f2bf(ar[4] * s2)  | (f2bf(ar[5] * s2)  << 16);
        p0.w = f2bf(ar[6] * s2)  | (f2bf(ar[7] * s2)  << 16);
        p1.x = f2bf(ar[8] * s2)  | (f2bf(ar[9] * s2)  << 16);
        p1.y = f2bf(ar[10] * s2) | (f2bf(ar[11] * s2) << 16);
        p1.z = f2bf(ar[12] * s2) | (f2bf(ar[13] * s2) << 16);
        p1.w = f2bf(ar[14] * s2) | (f2bf(ar[15] * s2) << 16);
        size_t o = (size_t)n * 8 + part * 2;
        xout[o] = p0;
        xout[o + 1] = p1;
    }
}

// Last layer: acc_out = (x0 + (y1+y2)*sd + rn*acc) / 4, rn=rsqrt(d), sd=sqrt(d).
__global__ __launch_bounds__(512) void pull_last_kernel(const int* __restrict__ bcnt,
                                                        const int* __restrict__ ps,
                                                        const uint4* __restrict__ xin,   // y2
                                                        const uint4* __restrict__ xprev, // y1
                                                        const float4* __restrict__ user,
                                                        const float4* __restrict__ item,
                                                        float4* __restrict__ acc4) {
    __shared__ unsigned sedge[SCAP];
    __shared__ int hist[128];
    __shared__ int scnt;
    __shared__ float accs[128 * 65];
    int hb = blockIdx.x;
    pull_accum(hb, bcnt, ps, xin, sedge, hist, &scnt, accs);
    int r = threadIdx.x >> 2, part = threadIdx.x & 3;
    int n = (hb << 7) + r;
    if (n < N_NODES) {
        int dg = hist[r];
        float d = (float)(dg < 1 ? 1 : dg);
        float rn = rsqrtf(d);
        float sd = sqrtf(d);
        int w0 = part * 2;
        uint4 p2a = xin  [(size_t)n * 8 + w0];
        uint4 p2b = xin  [(size_t)n * 8 + w0 + 1];
        uint4 p1a = xprev[(size_t)n * 8 + w0];
        uint4 p1b = xprev[(size_t)n * 8 + w0 + 1];
        const float4* x0 = (n < NUM_USERS) ? (user + (size_t)n * 16)
                                           : (item + (size_t)(n - NUM_USERS) * 16);
        float4 a0 = x0[w0 * 2], a1 = x0[w0 * 2 + 1], a2 = x0[w0 * 2 + 2], a3 = x0[w0 * 2 + 3];
        const float* ar = &accs[r * 65 + part * 16];
        float4 o0, o1, o2, o3;
        o0.x = (a0.x + (bflo(p1a.x) + bflo(p2a.x)) * sd + rn * ar[0])  * 0.25f;
        o0.y = (a0.y + (bfhi(p1a.x) + bfhi(p2a.x)) * sd + rn * ar[1])  * 0.25f;
        o0.z = (a0.z + (bflo(p1a.y) + bflo(p2a.y)) * sd + rn * ar[2])  * 0.25f;
        o0.w = (a0.w + (bfhi(p1a.y) + bfhi(p2a.y)) * sd + rn * ar[3])  * 0.25f;
        o1.x = (a1.x + (bflo(p1a.z) + bflo(p2a.z)) * sd + rn * ar[4])  * 0.25f;
        o1.y = (a1.y + (bfhi(p1a.z) + bfhi(p2a.z)) * sd + rn * ar[5])  * 0.25f;
        o1.z = (a1.z + (bflo(p1a.w) + bflo(p2a.w)) * sd + rn * ar[6])  * 0.25f;
        o1.w = (a1.w + (bfhi(p1a.w) + bfhi(p2a.w)) * sd + rn * ar[7])  * 0.25f;
        o2.x = (a2.x + (bflo(p1b.x) + bflo(p2b.x)) * sd + rn * ar[8])  * 0.25f;
        o2.y = (a2.y + (bfhi(p1b.x) + bfhi(p2b.x)) * sd + rn * ar[9])  * 0.25f;
        o2.z = (a2.z + (bflo(p1b.y) + bflo(p2b.y)) * sd + rn * ar[10]) * 0.25f;
        o2.w = (a2.w + (bfhi(p1b.y) + bfhi(p2b.y)) * sd + rn * ar[11]) * 0.25f;
        o3.x = (a3.x + (bflo(p1b.z) + bflo(p2b.z)) * sd + rn * ar[12]) * 0.25f;
        o3.y = (a3.y + (bfhi(p1b.z) + bfhi(p2b.z)) * sd + rn * ar[13]) * 0.25f;
        o3.z = (a3.z + (bflo(p1b.w) + bflo(p2b.w)) * sd + rn * ar[14]) * 0.25f;
        o3.w = (a3.w + (bfhi(p1b.w) + bfhi(p2b.w)) * sd + rn * ar[15]) * 0.25f;
        size_t o = (size_t)n * 16 + w0 * 2;
        acc4[o] = o0; acc4[o + 1] = o1; acc4[o + 2] = o2; acc4[o + 3] = o3;
    }
}

extern "C" void kernel_launch(void* const* d_in, const int* in_sizes, int n_in,
                              void* d_out, int out_size, void* d_ws, size_t ws_size,
                              hipStream_t stream) {
    const float* user = (const float*)d_in[0];
    const float* item = (const float*)d_in[1];
    const int*   ei   = (const int*)d_in[2];
    const int* row = ei;            // edge_index[0]
    const int* col = ei + N_EDGES;  // edge_index[1]

    char*  ws   = (char*)d_ws;
    int*   bcnt = (int*)(ws + OFF_BCNT);
    int*   ps   = (int*)(ws + OFF_PS);
    char*  xA   = ws + OFF_XA;   // bf16 y-tables
    char*  xB   = ws + OFF_XB;
    float* acc  = (float*)d_out;

    // CSR build: LDS-staged partition -> y0 (hist + streamed scale)
    hipMemsetAsync(bcnt, 0, 4096, stream);
    partition_kernel<<<PART_BLOCKS, 1024, 0, stream>>>((const int4*)row, (const int4*)col,
                                                       bcnt, (unsigned*)ps);
    y0_kernel<<<NHB, 512, 0, stream>>>(bcnt, ps,
                                       (const float4*)user, (const float4*)item,
                                       (uint2*)xA);

    // 3 pull layers: edge-parallel per half-bucket
    pull_kernel<<<NHB, 512, 0, stream>>>(bcnt, ps, (const uint4*)xA, (uint4*)xB);
    pull_kernel<<<NHB, 512, 0, stream>>>(bcnt, ps, (const uint4*)xB, (uint4*)xA);
    pull_last_kernel<<<NHB, 512, 0, stream>>>(bcnt, ps,
        (const uint4*)xA, (const uint4*)xB,
        (const float4*)user, (const float4*)item, (float4*)acc);
}

// Round 13
// 319.929 us; speedup vs baseline: 8.3846x; 8.3846x over previous
//
#include <hip/hip_runtime.h>

// LightGCN: final = (x0 + x1 + x2 + x3) / 4, x_{l+1}[r] = sum_{e:row=r} x_l[col_e]*norm_e
// norm_e = rsqrt(deg[row_e]) * rsqrt(deg[col_e]), deg = clip(bincount(row),1)
// N = 150000 nodes, d = 64, E = 2.4M edges. Output fp32.
//
// R25 = R22/R24 (verified 276.4us) + BUCKET-LOCAL degree sort.
// R21 lesson: GLOBAL degree sort broke be/scol/x0 line sharing (+17MB FETCH,
// +10% time). Fix: sort the 256 rows WITHIN each bucket by degree (iid
// degrees -> within-bucket sort gives adjacent-8 near-equal deg = wave
// uniformity), so reordered accesses stay in bucket-local windows (be 2KB,
// scol 18KB, x-rows 32KB, x0 64KB) that are L2-resident while the bucket's
// 8 pull blocks run. Sort lives in fine: 64-bin int-LDS hist + prefix +
// LDS-cursor scatter (R20/R23 lessons: int LDS atomics only). perm (600KB)
// fills the dead ex-rsqd region. Stores remain line-granular per node.
// x-tables stay 4096-B aligned (R15 lesson: misaligned rows = +122MB FETCH).

#define NUM_USERS 100000
#define NUM_ITEMS 50000
#define EMBED_DIM 64
#define N_NODES   150000
#define N_EDGES   2400000
#define N_BUCKETS 586       // ceil(150000/256), 256 rows per bucket
#define BCAP      4608      // static per-bucket window (ints)
#define PART_BLOCKS 256
#define MAX_BLK_EDGES 9376  // ceil(600000/256)*4

// ws layout (byte offsets), total 51,013,760 <= proven 51,033,344:
#define OFF_BCNT  0         // int32 x 586 (zeroed per launch)
#define OFF_BE    8192      // int2 x N {beg,end}            (ends 1,208,192; 128-aligned)
#define OFF_PERM  1208192   // int32 x N bucket-local degree-sorted ids (ends 1,808,192)
#define OFF_PS    1808256   // int32 x 586*4608 (128-aligned; ends 12,609,408)
#define OFF_XA    12611584  // bf16 x (N+1)*64 = 19,200,128  (4096-aligned; ends 31,811,712)
#define OFF_XB    31813632  // bf16 x (N+1)*64               (4096-aligned; ends 51,013,760)

__device__ __forceinline__ unsigned f2bf(float f) {  // RNE fp32 -> bf16 (as u16)
    unsigned u = __float_as_uint(f);
    return (u + 0x7fffu + ((u >> 16) & 1u)) >> 16;
}
__device__ __forceinline__ float bflo(unsigned u) { return __uint_as_float(u << 16); }
__device__ __forceinline__ float bfhi(unsigned u) { return __uint_as_float(u & 0xffff0000u); }
__device__ __forceinline__ float2 bf2(unsigned u) {  // bf16 pair -> float2
    float2 r; r.x = bflo(u); r.y = bfhi(u); return r;
}

// Pass 1: partition into static bucket windows, LDS-staged for coalesced
// writes. pack = (row&255)<<18 | col. Block 0 zeroes the dummy rows.
__global__ void partition_kernel(const int4* __restrict__ row4, const int4* __restrict__ col4,
                                 int* __restrict__ bcnt, unsigned* __restrict__ ps,
                                 uint2* __restrict__ yA, uint2* __restrict__ yB) {
    __shared__ int scanws[1024];                 // scan workspace (padded hist)
    __shared__ int lsize[N_BUCKETS];             // per-bucket count in this block
    __shared__ int lstart[N_BUCKETS + 1];        // exclusive starts in staged[]
    __shared__ int gbase[N_BUCKETS];             // reserved global bases
    __shared__ int lcur[N_BUCKETS];              // scatter cursors
    __shared__ unsigned staged[MAX_BLK_EDGES];   // bucket-sorted packed edges
    if (blockIdx.x == 0 && threadIdx.x < 16) {   // dummy row N_NODES of both tables
        uint2 z; z.x = 0u; z.y = 0u;
        yA[2400000 + threadIdx.x] = z;
        yB[2400000 + threadIdx.x] = z;
    }
    scanws[threadIdx.x] = 0;
    __syncthreads();
    const int total4 = N_EDGES / 4;
    int per4 = (total4 + gridDim.x - 1) / gridDim.x;
    int s4 = blockIdx.x * per4;
    int e4 = s4 + per4; if (e4 > total4) e4 = total4;
    const int cntE = (e4 - s4) * 4;
    // 1) histogram
    for (int i = s4 + (int)threadIdx.x; i < e4; i += (int)blockDim.x) {
        int4 r = row4[i];
        atomicAdd(&scanws[r.x >> 8], 1);
        atomicAdd(&scanws[r.y >> 8], 1);
        atomicAdd(&scanws[r.z >> 8], 1);
        atomicAdd(&scanws[r.w >> 8], 1);
    }
    __syncthreads();
    int myv = scanws[threadIdx.x];               // padded: 0 for t >= N_BUCKETS
    if (threadIdx.x < N_BUCKETS) lsize[threadIdx.x] = myv;
    __syncthreads();
    // 2) Hillis-Steele inclusive scan over 1024 (covers 586)
    for (int off = 1; off < 1024; off <<= 1) {
        int t = (threadIdx.x >= off) ? scanws[threadIdx.x - off] : 0;
        __syncthreads();
        scanws[threadIdx.x] += t;
        __syncthreads();
    }
    if (threadIdx.x < N_BUCKETS) {
        int incl = scanws[threadIdx.x];
        int st = incl - lsize[threadIdx.x];
        lstart[threadIdx.x] = st;
        lcur[threadIdx.x] = st;
        int c = lsize[threadIdx.x];
        gbase[threadIdx.x] = c ? (threadIdx.x * BCAP + atomicAdd(&bcnt[threadIdx.x], c)) : 0;
    }
    if (threadIdx.x == 0) lstart[N_BUCKETS] = cntE;
    __syncthreads();
    // 3) scatter into bucket-sorted LDS
    for (int i = s4 + (int)threadIdx.x; i < e4; i += (int)blockDim.x) {
        int4 r = row4[i];
        int4 c = col4[i];
        int pos;
        pos = atomicAdd(&lcur[r.x >> 8], 1); staged[pos] = ((unsigned)(r.x & 255) << 18) | (unsigned)c.x;
        pos = atomicAdd(&lcur[r.y >> 8], 1); staged[pos] = ((unsigned)(r.y & 255) << 18) | (unsigned)c.y;
        pos = atomicAdd(&lcur[r.z >> 8], 1); staged[pos] = ((unsigned)(r.z & 255) << 18) | (unsigned)c.z;
        pos = atomicAdd(&lcur[r.w >> 8], 1); staged[pos] = ((unsigned)(r.w & 255) << 18) | (unsigned)c.w;
    }
    __syncthreads();
    // 4) sequential writeback: consecutive i -> consecutive dest within runs
    for (int i = (int)threadIdx.x; i < cntE; i += (int)blockDim.x) {
        int lo = 0, hi = N_BUCKETS - 1;          // largest b with lstart[b] <= i
        while (lo < hi) {
            int mid = (lo + hi + 1) >> 1;
            if (lstart[mid] <= i) lo = mid; else hi = mid - 1;
        }
        ps[gbase[lo] + (i - lstart[lo])] = staged[i];
    }
}

// Pass 2: one block (512 thr) per bucket. Stage bucket edges in LDS, build
// 256-row hist, even-padded row starts, be, in-place sorted writeback
// (row bits stripped), y0 = x0*rsqrt(deg) rows, and bucket-local degree
// sort -> perm (64-bin counting sort, int LDS atomics only).
__global__ void fine_kernel(const int* __restrict__ bcnt, int* __restrict__ ps,
                            int2* __restrict__ be, int* __restrict__ perm,
                            const float4* __restrict__ user, const float4* __restrict__ item,
                            uint2* __restrict__ yA) {
    __shared__ int ledge[BCAP];
    __shared__ int rh[256];
    __shared__ int rsc[256];
    __shared__ int rcur[256];
    __shared__ float rq[256];
    __shared__ int dh[64];       // degree-bin hist (bin = min(deg,63)), then cursor
    __shared__ int dbase[64];    // exclusive prefix within bucket
    int b = blockIdx.x;
    int base = b * BCAP;
    int cnt  = bcnt[b];
    if (cnt > BCAP) cnt = BCAP;          // defensive (never expected)
    if (threadIdx.x < 256) rh[threadIdx.x] = 0;
    if (threadIdx.x < 64) dh[threadIdx.x] = 0;
    __syncthreads();
    for (int i = threadIdx.x; i < cnt; i += blockDim.x) {
        int p = ps[base + i];
        ledge[i] = p;
        atomicAdd(&rh[p >> 18], 1);
    }
    __syncthreads();
    if (threadIdx.x < 256) rsc[threadIdx.x] = (rh[threadIdx.x] + 1) & ~1;  // even row size
    __syncthreads();
    for (int off = 1; off < 256; off <<= 1) {
        int t = (threadIdx.x < 256 && threadIdx.x >= off) ? rsc[threadIdx.x - off] : 0;
        __syncthreads();
        if (threadIdx.x < 256) rsc[threadIdx.x] += t;
        __syncthreads();
    }
    if (threadIdx.x < 256) {
        int r = threadIdx.x;
        int sz = (rh[r] + 1) & ~1;
        int pstart = rsc[r] - sz;            // even (base even, sizes even)
        rcur[r] = pstart;
        int n = (b << 8) + r;
        if (n < N_NODES) {
            int2 p; p.x = base + pstart; p.y = base + pstart + rh[r];
            be[n] = p;
            float d = (float)(rh[r] < 1 ? 1 : rh[r]);
            rq[r] = rsqrtf(d);
            int bin = rh[r] < 63 ? rh[r] : 63;
            atomicAdd(&dh[bin], 1);          // valid rows only
        }
    }
    __syncthreads();
    if (threadIdx.x < 64) {                  // exclusive prefix over 64 bins
        int s = 0;
        for (int bb = 0; bb < (int)threadIdx.x; ++bb) s += dh[bb];
        dbase[threadIdx.x] = s;
    }
    __syncthreads();
    if (threadIdx.x < 64) dh[threadIdx.x] = 0;   // reuse as scatter cursor
    __syncthreads();
    if (threadIdx.x < 256) {
        int r = threadIdx.x;
        int n = (b << 8) + r;
        if (n < N_NODES) {
            int bin = rh[r] < 63 ? rh[r] : 63;
            int pos = dbase[bin] + atomicAdd(&dh[bin], 1);
            perm[(b << 8) + pos] = n;        // valid rows fill slots 0..valid-1
        }
    }
    __syncthreads();
    for (int i = threadIdx.x; i < cnt; i += blockDim.x) {
        int p = ledge[i];
        int pos = atomicAdd(&rcur[p >> 18], 1);      // LDS atomic
        ps[base + pos] = p & 0x3FFFF;                // sorted col, row bits stripped
    }
    // y0 rows for this bucket: 256 rows x 16 uint2 words; word w covers float4 w.
    for (int idx = threadIdx.x; idx < 4096; idx += blockDim.x) {
        int r = idx >> 4, w = idx & 15;
        int n = (b << 8) + r;
        if (n < N_NODES) {
            const float4* src = (n < NUM_USERS) ? (user + (size_t)n * 16)
                                                : (item + (size_t)(n - NUM_USERS) * 16);
            float4 v = src[w];
            float rn = rq[r];
            uint2 o;
            o.x = f2bf(v.x * rn) | (f2bf(v.y * rn) << 16);
            o.y = f2bf(v.z * rn) | (f2bf(v.w * rn) << 16);
            yA[(size_t)n * 16 + w] = o;
        }
    }
}

// 8 lanes per node, 8 nodes per wave, bucket-local degree-sorted order
// (perm maps slot -> node within the SAME bucket: wave uniformity without
// losing window locality -- R21 lesson). Lane q owns dims [8q,8q+8);
// 8-edge unroll: 4 int2 scol + 8 uint4 gathers in flight. OOB -> dummy
// zero row N_NODES, predicated BEFORE addressing. Over-read <=24B past ps
// end lands in the 2176-B slack before XA.
__device__ __forceinline__ void pull_sum(int2 bnd, int q,
                                         const int2* __restrict__ scol2,
                                         const uint4* __restrict__ xin, float2 sum[4]) {
    int endj = bnd.y;
    for (int j = bnd.x; j < endj; j += 8) {
        int h = j >> 1;
        int2 cc0 = scol2[h];
        int2 cc1 = scol2[h + 1];
        int2 cc2 = scol2[h + 2];
        int2 cc3 = scol2[h + 3];
        int c0 = cc0.x;                               // j < endj by loop cond
        int c1 = (j + 1 < endj) ? cc0.y : N_NODES;
        int c2 = (j + 2 < endj) ? cc1.x : N_NODES;
        int c3 = (j + 3 < endj) ? cc1.y : N_NODES;
        int c4 = (j + 4 < endj) ? cc2.x : N_NODES;
        int c5 = (j + 5 < endj) ? cc2.y : N_NODES;
        int c6 = (j + 6 < endj) ? cc3.x : N_NODES;
        int c7 = (j + 7 < endj) ? cc3.y : N_NODES;
        uint4 X0 = xin[(size_t)c0 * 8 + q];
        uint4 X1 = xin[(size_t)c1 * 8 + q];
        uint4 X2 = xin[(size_t)c2 * 8 + q];
        uint4 X3 = xin[(size_t)c3 * 8 + q];
        uint4 X4 = xin[(size_t)c4 * 8 + q];
        uint4 X5 = xin[(size_t)c5 * 8 + q];
        uint4 X6 = xin[(size_t)c6 * 8 + q];
        uint4 X7 = xin[(size_t)c7 * 8 + q];
        sum[0] += (bf2(X0.x) + bf2(X1.x)) + (bf2(X2.x) + bf2(X3.x))
                + (bf2(X4.x) + bf2(X5.x)) + (bf2(X6.x) + bf2(X7.x));
        sum[1] += (bf2(X0.y) + bf2(X1.y)) + (bf2(X2.y) + bf2(X3.y))
                + (bf2(X4.y) + bf2(X5.y)) + (bf2(X6.y) + bf2(X7.y));
        sum[2] += (bf2(X0.z) + bf2(X1.z)) + (bf2(X2.z) + bf2(X3.z))
                + (bf2(X4.z) + bf2(X5.z)) + (bf2(X6.z) + bf2(X7.z));
        sum[3] += (bf2(X0.w) + bf2(X1.w)) + (bf2(X2.w) + bf2(X3.w))
                + (bf2(X4.w) + bf2(X5.w)) + (bf2(X6.w) + bf2(X7.w));
    }
}

// Middle layers: y_{l+1}[pn] = rsqrt(deg)^2 * sum  (bf16). All 64 lanes store.
__global__ void pull_kernel(const int* __restrict__ perm, const int2* __restrict__ be,
                            const int2* __restrict__ scol2,
                            const uint4* __restrict__ xin, uint4* __restrict__ xout) {
    int t = blockIdx.x * blockDim.x + (int)threadIdx.x;
    int n = t >> 3;
    if (n >= N_NODES) return;
    int pn = perm[n];
    int q = t & 7;
    int2 bnd = be[pn];
    float2 sum[4];
    sum[0] = make_float2(0.f, 0.f); sum[1] = make_float2(0.f, 0.f);
    sum[2] = make_float2(0.f, 0.f); sum[3] = make_float2(0.f, 0.f);
    pull_sum(bnd, q, scol2, xin, sum);
    int deg = bnd.y - bnd.x;
    float d = (float)(deg < 1 ? 1 : deg);
    float rn = rsqrtf(d);
    float s2 = rn * rn;
    uint4 p;
    p.x = f2bf(sum[0].x * s2) | (f2bf(sum[0].y * s2) << 16);
    p.y = f2bf(sum[1].x * s2) | (f2bf(sum[1].y * s2) << 16);
    p.z = f2bf(sum[2].x * s2) | (f2bf(sum[2].y * s2) << 16);
    p.w = f2bf(sum[3].x * s2) | (f2bf(sum[3].y * s2) << 16);
    xout[(size_t)pn * 8 + q] = p;
}

// Last layer: acc = (x0 + (y1+y2)*sd + rn*sum) / 4, rn = rsqrt(deg), sd = sqrt(deg).
__global__ void pull_last_kernel(const int* __restrict__ perm, const int2* __restrict__ be,
                                 const int2* __restrict__ scol2,
                                 const uint4* __restrict__ xin,   // y2 (gather table)
                                 const uint4* __restrict__ xprev, // y1
                                 const float4* __restrict__ user, const float4* __restrict__ item,
                                 float4* __restrict__ acc4) {
    int t = blockIdx.x * blockDim.x + (int)threadIdx.x;
    int n = t >> 3;
    if (n >= N_NODES) return;
    int pn = perm[n];
    int q = t & 7;
    int2 bnd = be[pn];
    float2 sum[4];
    sum[0] = make_float2(0.f, 0.f); sum[1] = make_float2(0.f, 0.f);
    sum[2] = make_float2(0.f, 0.f); sum[3] = make_float2(0.f, 0.f);
    pull_sum(bnd, q, scol2, xin, sum);
    int deg = bnd.y - bnd.x;
    float d = (float)(deg < 1 ? 1 : deg);
    float rn = rsqrtf(d);
    float sd = sqrtf(d);
    uint4 p2 = xin  [(size_t)pn * 8 + q];
    uint4 p1 = xprev[(size_t)pn * 8 + q];
    const float4* x0 = (pn < NUM_USERS) ? (user + (size_t)pn * 16)
                                        : (item + (size_t)(pn - NUM_USERS) * 16);
    float4 a0 = x0[q * 2], a1 = x0[q * 2 + 1];
    float4 o0, o1;
    o0.x = (a0.x + (bflo(p1.x) + bflo(p2.x)) * sd + rn * sum[0].x) * 0.25f;
    o0.y = (a0.y + (bfhi(p1.x) + bfhi(p2.x)) * sd + rn * sum[0].y) * 0.25f;
    o0.z = (a0.z + (bflo(p1.y) + bflo(p2.y)) * sd + rn * sum[1].x) * 0.25f;
    o0.w = (a0.w + (bfhi(p1.y) + bfhi(p2.y)) * sd + rn * sum[1].y) * 0.25f;
    o1.x = (a1.x + (bflo(p1.z) + bflo(p2.z)) * sd + rn * sum[2].x) * 0.25f;
    o1.y = (a1.y + (bfhi(p1.z) + bfhi(p2.z)) * sd + rn * sum[2].y) * 0.25f;
    o1.z = (a1.z + (bflo(p1.w) + bflo(p2.w)) * sd + rn * sum[3].x) * 0.25f;
    o1.w = (a1.w + (bfhi(p1.w) + bfhi(p2.w)) * sd + rn * sum[3].y) * 0.25f;
    size_t o4 = (size_t)pn * 16 + q * 2;
    acc4[o4] = o0;
    acc4[o4 + 1] = o1;
}

extern "C" void kernel_launch(void* const* d_in, const int* in_sizes, int n_in,
                              void* d_out, int out_size, void* d_ws, size_t ws_size,
                              hipStream_t stream) {
    const float* user = (const float*)d_in[0];
    const float* item = (const float*)d_in[1];
    const int*   ei   = (const int*)d_in[2];
    const int* row = ei;            // edge_index[0]
    const int* col = ei + N_EDGES;  // edge_index[1]

    char*  ws   = (char*)d_ws;
    int*   bcnt = (int*)(ws + OFF_BCNT);
    int2*  be   = (int2*)(ws + OFF_BE);
    int*   perm = (int*)(ws + OFF_PERM);
    int*   ps   = (int*)(ws + OFF_PS);
    char*  xA   = ws + OFF_XA;   // bf16 y-tables, (N+1) rows (row N = zeros)
    char*  xB   = ws + OFF_XB;
    float* acc  = (float*)d_out;

    // CSR build: LDS-staged partition -> fine (sort + be + y0 + local perm)
    hipMemsetAsync(bcnt, 0, 4096, stream);
    partition_kernel<<<PART_BLOCKS, 1024, 0, stream>>>((const int4*)row, (const int4*)col,
                                                       bcnt, (unsigned*)ps,
                                                       (uint2*)xA, (uint2*)xB);
    fine_kernel<<<N_BUCKETS, 512, 0, stream>>>(bcnt, ps, be, perm,
                                               (const float4*)user, (const float4*)item,
                                               (uint2*)xA);

    // 3 pull layers: 8 threads per node, bucket-local degree-sorted order
    const int grid = (N_NODES * 8 + 255) / 256;
    pull_kernel<<<grid, 256, 0, stream>>>(perm, be, (const int2*)ps,
        (const uint4*)xA, (uint4*)xB);
    pull_kernel<<<grid, 256, 0, stream>>>(perm, be, (const int2*)ps,
        (const uint4*)xB, (uint4*)xA);
    pull_last_kernel<<<grid, 256, 0, stream>>>(perm, be, (const int2*)ps,
        (const uint4*)xA, (const uint4*)xB,
        (const float4*)user, (const float4*)item, (float4*)acc);
}

// Round 14
// 281.095 us; speedup vs baseline: 9.5430x; 1.1382x over previous
//
#include <hip/hip_runtime.h>

// LightGCN: final = (x0 + x1 + x2 + x3) / 4, x_{l+1}[r] = sum_{e:row=r} x_l[col_e]*norm_e
// norm_e = rsqrt(deg[row_e]) * rsqrt(deg[col_e]), deg = clip(bincount(row),1)
// N = 150000 nodes, d = 64, E = 2.4M edges. Output fp32.
//
// R26 = R22/R24 (verified 276.4us) + STAGGERED bucket reservation.
// R25 lesson (with R21): ANY node reorder (even bucket-local) loses more
// store/line locality than divergence saves -> identity order is final.
// New fix target: partition's reservation phase issued 256 blocks x 586
// atomics in IDENTICAL bucket order -> per-counter serial chains of depth
// 256 (~170ns/hop, cf. R20's 393us/2344-deep) ~= 43us hidden in partition.
// Stagger: thread t reserves bucket (t + 37*blockIdx.x) % 586 so chains
// spread across the phase. Reservations are disjoint slices under any
// arrival order -> correctness unchanged. All else identical to R22.
// Standing lessons: int LDS atomics only (R23); x-tables 4096-B aligned
// (R15); identity node order (R21/R25).

#define NUM_USERS 100000
#define NUM_ITEMS 50000
#define EMBED_DIM 64
#define N_NODES   150000
#define N_EDGES   2400000
#define N_BUCKETS 586       // ceil(150000/256), 256 rows per bucket
#define BCAP      4608      // static per-bucket window (ints)
#define PART_BLOCKS 256
#define MAX_BLK_EDGES 9376  // ceil(600000/256)*4

// ws layout (byte offsets), total 51,013,760 <= proven 51,033,344:
#define OFF_BCNT  0         // int32 x 586 (zeroed per launch)
#define OFF_BE    8192      // int2 x N {beg,end}            (ends 1,208,192; 128-aligned)
#define OFF_PS    1808256   // int32 x 586*4608 (128-aligned; ends 12,609,408)
#define OFF_XA    12611584  // bf16 x (N+1)*64 = 19,200,128  (4096-aligned; ends 31,811,712)
#define OFF_XB    31813632  // bf16 x (N+1)*64               (4096-aligned; ends 51,013,760)

__device__ __forceinline__ unsigned f2bf(float f) {  // RNE fp32 -> bf16 (as u16)
    unsigned u = __float_as_uint(f);
    return (u + 0x7fffu + ((u >> 16) & 1u)) >> 16;
}
__device__ __forceinline__ float bflo(unsigned u) { return __uint_as_float(u << 16); }
__device__ __forceinline__ float bfhi(unsigned u) { return __uint_as_float(u & 0xffff0000u); }
__device__ __forceinline__ float2 bf2(unsigned u) {  // bf16 pair -> float2
    float2 r; r.x = bflo(u); r.y = bfhi(u); return r;
}

// Pass 1: partition into static bucket windows, LDS-staged for coalesced
// writes. pack = (row&255)<<18 | col. Block 0 zeroes the dummy rows.
__global__ void partition_kernel(const int4* __restrict__ row4, const int4* __restrict__ col4,
                                 int* __restrict__ bcnt, unsigned* __restrict__ ps,
                                 uint2* __restrict__ yA, uint2* __restrict__ yB) {
    __shared__ int scanws[1024];                 // scan workspace (padded hist)
    __shared__ int lsize[N_BUCKETS];             // per-bucket count in this block
    __shared__ int lstart[N_BUCKETS + 1];        // exclusive starts in staged[]
    __shared__ int gbase[N_BUCKETS];             // reserved global bases
    __shared__ int lcur[N_BUCKETS];              // scatter cursors
    __shared__ unsigned staged[MAX_BLK_EDGES];   // bucket-sorted packed edges
    if (blockIdx.x == 0 && threadIdx.x < 16) {   // dummy row N_NODES of both tables
        uint2 z; z.x = 0u; z.y = 0u;
        yA[2400000 + threadIdx.x] = z;
        yB[2400000 + threadIdx.x] = z;
    }
    scanws[threadIdx.x] = 0;
    __syncthreads();
    const int total4 = N_EDGES / 4;
    int per4 = (total4 + gridDim.x - 1) / gridDim.x;
    int s4 = blockIdx.x * per4;
    int e4 = s4 + per4; if (e4 > total4) e4 = total4;
    const int cntE = (e4 - s4) * 4;
    // 1) histogram
    for (int i = s4 + (int)threadIdx.x; i < e4; i += (int)blockDim.x) {
        int4 r = row4[i];
        atomicAdd(&scanws[r.x >> 8], 1);
        atomicAdd(&scanws[r.y >> 8], 1);
        atomicAdd(&scanws[r.z >> 8], 1);
        atomicAdd(&scanws[r.w >> 8], 1);
    }
    __syncthreads();
    int myv = scanws[threadIdx.x];               // padded: 0 for t >= N_BUCKETS
    if (threadIdx.x < N_BUCKETS) lsize[threadIdx.x] = myv;
    __syncthreads();
    // 2) Hillis-Steele inclusive scan over 1024 (covers 586)
    for (int off = 1; off < 1024; off <<= 1) {
        int t = (threadIdx.x >= off) ? scanws[threadIdx.x - off] : 0;
        __syncthreads();
        scanws[threadIdx.x] += t;
        __syncthreads();
    }
    if (threadIdx.x < N_BUCKETS) {
        int incl = scanws[threadIdx.x];
        int st = incl - lsize[threadIdx.x];
        lstart[threadIdx.x] = st;
        lcur[threadIdx.x] = st;
    }
    if (threadIdx.x == 0) lstart[N_BUCKETS] = cntE;
    __syncthreads();
    // 2b) STAGGERED global reservation: thread t reserves bucket
    // (t + 37*blockIdx.x) % 586 so the 256 blocks' atomics to any one
    // counter spread across the phase instead of forming a 256-deep
    // serial chain (R20 lesson, quantified: ~170ns/hop).
    if (threadIdx.x < N_BUCKETS) {
        int g = (int)((threadIdx.x + 37u * blockIdx.x) % N_BUCKETS);
        int c = lsize[g];
        gbase[g] = c ? (g * BCAP + atomicAdd(&bcnt[g], c)) : 0;
    }
    __syncthreads();
    // 3) scatter into bucket-sorted LDS
    for (int i = s4 + (int)threadIdx.x; i < e4; i += (int)blockDim.x) {
        int4 r = row4[i];
        int4 c = col4[i];
        int pos;
        pos = atomicAdd(&lcur[r.x >> 8], 1); staged[pos] = ((unsigned)(r.x & 255) << 18) | (unsigned)c.x;
        pos = atomicAdd(&lcur[r.y >> 8], 1); staged[pos] = ((unsigned)(r.y & 255) << 18) | (unsigned)c.y;
        pos = atomicAdd(&lcur[r.z >> 8], 1); staged[pos] = ((unsigned)(r.z & 255) << 18) | (unsigned)c.z;
        pos = atomicAdd(&lcur[r.w >> 8], 1); staged[pos] = ((unsigned)(r.w & 255) << 18) | (unsigned)c.w;
    }
    __syncthreads();
    // 4) sequential writeback: consecutive i -> consecutive dest within runs
    for (int i = (int)threadIdx.x; i < cntE; i += (int)blockDim.x) {
        int lo = 0, hi = N_BUCKETS - 1;          // largest b with lstart[b] <= i
        while (lo < hi) {
            int mid = (lo + hi + 1) >> 1;
            if (lstart[mid] <= i) lo = mid; else hi = mid - 1;
        }
        ps[gbase[lo] + (i - lstart[lo])] = staged[i];
    }
}

// Pass 2: one block (512 thr) per bucket. Stage bucket edges in LDS, build
// 256-row hist, even-padded row starts, be, in-place sorted writeback
// (row bits stripped), and y0 = x0*rsqrt(deg) rows.
__global__ void fine_kernel(const int* __restrict__ bcnt, int* __restrict__ ps,
                            int2* __restrict__ be,
                            const float4* __restrict__ user, const float4* __restrict__ item,
                            uint2* __restrict__ yA) {
    __shared__ int ledge[BCAP];
    __shared__ int rh[256];
    __shared__ int rsc[256];
    __shared__ int rcur[256];
    __shared__ float rq[256];
    int b = blockIdx.x;
    int base = b * BCAP;
    int cnt  = bcnt[b];
    if (cnt > BCAP) cnt = BCAP;          // defensive (never expected)
    if (threadIdx.x < 256) rh[threadIdx.x] = 0;
    __syncthreads();
    for (int i = threadIdx.x; i < cnt; i += blockDim.x) {
        int p = ps[base + i];
        ledge[i] = p;
        atomicAdd(&rh[p >> 18], 1);
    }
    __syncthreads();
    if (threadIdx.x < 256) rsc[threadIdx.x] = (rh[threadIdx.x] + 1) & ~1;  // even row size
    __syncthreads();
    for (int off = 1; off < 256; off <<= 1) {
        int t = (threadIdx.x < 256 && threadIdx.x >= off) ? rsc[threadIdx.x - off] : 0;
        __syncthreads();
        if (threadIdx.x < 256) rsc[threadIdx.x] += t;
        __syncthreads();
    }
    if (threadIdx.x < 256) {
        int r = threadIdx.x;
        int sz = (rh[r] + 1) & ~1;
        int pstart = rsc[r] - sz;            // even (base even, sizes even)
        rcur[r] = pstart;
        int n = (b << 8) + r;
        if (n < N_NODES) {
            int2 p; p.x = base + pstart; p.y = base + pstart + rh[r];
            be[n] = p;
            float d = (float)(rh[r] < 1 ? 1 : rh[r]);
            rq[r] = rsqrtf(d);
        }
    }
    __syncthreads();
    for (int i = threadIdx.x; i < cnt; i += blockDim.x) {
        int p = ledge[i];
        int pos = atomicAdd(&rcur[p >> 18], 1);      // LDS atomic
        ps[base + pos] = p & 0x3FFFF;                // sorted col, row bits stripped
    }
    // y0 rows for this bucket: 256 rows x 16 uint2 words; word w covers float4 w.
    for (int idx = threadIdx.x; idx < 4096; idx += blockDim.x) {
        int r = idx >> 4, w = idx & 15;
        int n = (b << 8) + r;
        if (n < N_NODES) {
            const float4* src = (n < NUM_USERS) ? (user + (size_t)n * 16)
                                                : (item + (size_t)(n - NUM_USERS) * 16);
            float4 v = src[w];
            float rn = rq[r];
            uint2 o;
            o.x = f2bf(v.x * rn) | (f2bf(v.y * rn) << 16);
            o.y = f2bf(v.z * rn) | (f2bf(v.w * rn) << 16);
            yA[(size_t)n * 16 + w] = o;
        }
    }
}

// 8 lanes per node, 8 nodes per wave (identity order: consecutive nodes ->
// contiguous scol runs + contiguous stores; R21/R25 lesson: ANY reorder
// loses). Lane q owns dims [8q,8q+8); 8-edge unroll: 4 int2 scol + 8 uint4
// gathers in flight. OOB -> dummy zero row N_NODES, predicated BEFORE
// addressing. Over-read <=24B past ps end lands in the slack before XA.
__device__ __forceinline__ void pull_sum(int2 bnd, int q,
                                         const int2* __restrict__ scol2,
                                         const uint4* __restrict__ xin, float2 sum[4]) {
    int endj = bnd.y;
    for (int j = bnd.x; j < endj; j += 8) {
        int h = j >> 1;
        int2 cc0 = scol2[h];
        int2 cc1 = scol2[h + 1];
        int2 cc2 = scol2[h + 2];
        int2 cc3 = scol2[h + 3];
        int c0 = cc0.x;                               // j < endj by loop cond
        int c1 = (j + 1 < endj) ? cc0.y : N_NODES;
        int c2 = (j + 2 < endj) ? cc1.x : N_NODES;
        int c3 = (j + 3 < endj) ? cc1.y : N_NODES;
        int c4 = (j + 4 < endj) ? cc2.x : N_NODES;
        int c5 = (j + 5 < endj) ? cc2.y : N_NODES;
        int c6 = (j + 6 < endj) ? cc3.x : N_NODES;
        int c7 = (j + 7 < endj) ? cc3.y : N_NODES;
        uint4 X0 = xin[(size_t)c0 * 8 + q];
        uint4 X1 = xin[(size_t)c1 * 8 + q];
        uint4 X2 = xin[(size_t)c2 * 8 + q];
        uint4 X3 = xin[(size_t)c3 * 8 + q];
        uint4 X4 = xin[(size_t)c4 * 8 + q];
        uint4 X5 = xin[(size_t)c5 * 8 + q];
        uint4 X6 = xin[(size_t)c6 * 8 + q];
        uint4 X7 = xin[(size_t)c7 * 8 + q];
        sum[0] += (bf2(X0.x) + bf2(X1.x)) + (bf2(X2.x) + bf2(X3.x))
                + (bf2(X4.x) + bf2(X5.x)) + (bf2(X6.x) + bf2(X7.x));
        sum[1] += (bf2(X0.y) + bf2(X1.y)) + (bf2(X2.y) + bf2(X3.y))
                + (bf2(X4.y) + bf2(X5.y)) + (bf2(X6.y) + bf2(X7.y));
        sum[2] += (bf2(X0.z) + bf2(X1.z)) + (bf2(X2.z) + bf2(X3.z))
                + (bf2(X4.z) + bf2(X5.z)) + (bf2(X6.z) + bf2(X7.z));
        sum[3] += (bf2(X0.w) + bf2(X1.w)) + (bf2(X2.w) + bf2(X3.w))
                + (bf2(X4.w) + bf2(X5.w)) + (bf2(X6.w) + bf2(X7.w));
    }
}

// Middle layers: y_{l+1}[n] = rsqrt(deg)^2 * sum  (bf16). All 64 lanes store.
__global__ void pull_kernel(const int2* __restrict__ be,
                            const int2* __restrict__ scol2,
                            const uint4* __restrict__ xin, uint4* __restrict__ xout) {
    int t = blockIdx.x * blockDim.x + (int)threadIdx.x;
    int n = t >> 3;
    if (n >= N_NODES) return;
    int q = t & 7;
    int2 bnd = be[n];
    float2 sum[4];
    sum[0] = make_float2(0.f, 0.f); sum[1] = make_float2(0.f, 0.f);
    sum[2] = make_float2(0.f, 0.f); sum[3] = make_float2(0.f, 0.f);
    pull_sum(bnd, q, scol2, xin, sum);
    int deg = bnd.y - bnd.x;
    float d = (float)(deg < 1 ? 1 : deg);
    float rn = rsqrtf(d);
    float s2 = rn * rn;
    uint4 p;
    p.x = f2bf(sum[0].x * s2) | (f2bf(sum[0].y * s2) << 16);
    p.y = f2bf(sum[1].x * s2) | (f2bf(sum[1].y * s2) << 16);
    p.z = f2bf(sum[2].x * s2) | (f2bf(sum[2].y * s2) << 16);
    p.w = f2bf(sum[3].x * s2) | (f2bf(sum[3].y * s2) << 16);
    xout[(size_t)n * 8 + q] = p;
}

// Last layer: acc = (x0 + (y1+y2)*sd + rn*sum) / 4, rn = rsqrt(deg), sd = sqrt(deg).
__global__ void pull_last_kernel(const int2* __restrict__ be,
                                 const int2* __restrict__ scol2,
                                 const uint4* __restrict__ xin,   // y2 (gather table)
                                 const uint4* __restrict__ xprev, // y1
                                 const float4* __restrict__ user, const float4* __restrict__ item,
                                 float4* __restrict__ acc4) {
    int t = blockIdx.x * blockDim.x + (int)threadIdx.x;
    int n = t >> 3;
    if (n >= N_NODES) return;
    int q = t & 7;
    int2 bnd = be[n];
    float2 sum[4];
    sum[0] = make_float2(0.f, 0.f); sum[1] = make_float2(0.f, 0.f);
    sum[2] = make_float2(0.f, 0.f); sum[3] = make_float2(0.f, 0.f);
    pull_sum(bnd, q, scol2, xin, sum);
    int deg = bnd.y - bnd.x;
    float d = (float)(deg < 1 ? 1 : deg);
    float rn = rsqrtf(d);
    float sd = sqrtf(d);
    uint4 p2 = xin  [(size_t)n * 8 + q];
    uint4 p1 = xprev[(size_t)n * 8 + q];
    const float4* x0 = (n < NUM_USERS) ? (user + (size_t)n * 16)
                                       : (item + (size_t)(n - NUM_USERS) * 16);
    float4 a0 = x0[q * 2], a1 = x0[q * 2 + 1];
    float4 o0, o1;
    o0.x = (a0.x + (bflo(p1.x) + bflo(p2.x)) * sd + rn * sum[0].x) * 0.25f;
    o0.y = (a0.y + (bfhi(p1.x) + bfhi(p2.x)) * sd + rn * sum[0].y) * 0.25f;
    o0.z = (a0.z + (bflo(p1.y) + bflo(p2.y)) * sd + rn * sum[1].x) * 0.25f;
    o0.w = (a0.w + (bfhi(p1.y) + bfhi(p2.y)) * sd + rn * sum[1].y) * 0.25f;
    o1.x = (a1.x + (bflo(p1.z) + bflo(p2.z)) * sd + rn * sum[2].x) * 0.25f;
    o1.y = (a1.y + (bfhi(p1.z) + bfhi(p2.z)) * sd + rn * sum[2].y) * 0.25f;
    o1.z = (a1.z + (bflo(p1.w) + bflo(p2.w)) * sd + rn * sum[3].x) * 0.25f;
    o1.w = (a1.w + (bfhi(p1.w) + bfhi(p2.w)) * sd + rn * sum[3].y) * 0.25f;
    size_t o4 = (size_t)n * 16 + q * 2;
    acc4[o4] = o0;
    acc4[o4 + 1] = o1;
}

extern "C" void kernel_launch(void* const* d_in, const int* in_sizes, int n_in,
                              void* d_out, int out_size, void* d_ws, size_t ws_size,
                              hipStream_t stream) {
    const float* user = (const float*)d_in[0];
    const float* item = (const float*)d_in[1];
    const int*   ei   = (const int*)d_in[2];
    const int* row = ei;            // edge_index[0]
    const int* col = ei + N_EDGES;  // edge_index[1]

    char*  ws   = (char*)d_ws;
    int*   bcnt = (int*)(ws + OFF_BCNT);
    int2*  be   = (int2*)(ws + OFF_BE);
    int*   ps   = (int*)(ws + OFF_PS);
    char*  xA   = ws + OFF_XA;   // bf16 y-tables, (N+1) rows (row N = zeros)
    char*  xB   = ws + OFF_XB;
    float* acc  = (float*)d_out;

    // CSR build: LDS-staged partition (staggered reservation) -> fine
    hipMemsetAsync(bcnt, 0, 4096, stream);
    partition_kernel<<<PART_BLOCKS, 1024, 0, stream>>>((const int4*)row, (const int4*)col,
                                                       bcnt, (unsigned*)ps,
                                                       (uint2*)xA, (uint2*)xB);
    fine_kernel<<<N_BUCKETS, 512, 0, stream>>>(bcnt, ps, be,
                                               (const float4*)user, (const float4*)item,
                                               (uint2*)xA);

    // 3 pull layers: 8 threads per node, identity node order
    const int grid = (N_NODES * 8 + 255) / 256;
    pull_kernel<<<grid, 256, 0, stream>>>(be, (const int2*)ps,
        (const uint4*)xA, (uint4*)xB);
    pull_kernel<<<grid, 256, 0, stream>>>(be, (const int2*)ps,
        (const uint4*)xB, (uint4*)xA);
    pull_last_kernel<<<grid, 256, 0, stream>>>(be, (const int2*)ps,
        (const uint4*)xA, (const uint4*)xB,
        (const float4*)user, (const float4*)item, (float4*)acc);
}

// Round 15
// 267.784 us; speedup vs baseline: 10.0173x; 1.0497x over previous
//
#include <hip/hip_runtime.h>

// LightGCN: final = (x0 + x1 + x2 + x3) / 4, x_{l+1}[r] = sum_{e:row=r} x_l[col_e]*norm_e
// norm_e = rsqrt(deg[row_e]) * rsqrt(deg[col_e]), deg = clip(bincount(row),1)
// N = 150000 nodes, d = 64, E = 2.4M edges. Output fp32.
//
// R27 = R22 (verified 276.4us; stagger of R26 reverted, was -1.7%) +
// fine LDS-staged sorted writeback. fine's row-sort scattered 2.4M 4-B
// global writes into 18-KB windows (~64B line traffic each ~= 154MB ~=
// 25us) -- same pathology R22 fixed in partition. Now: scatter into LDS
// lsort[BCAP] (int LDS ops only, R23 lesson), then sequential coalesced
// writeback. Pad slots stay garbage (pull predicates discard before
// address formation -- unchanged invariant).
// Standing lessons: identity node order (R21/R25); int LDS atomics only
// (R23); x-tables 4096-B aligned (R15); reservation order plain (R26).

#define NUM_USERS 100000
#define NUM_ITEMS 50000
#define EMBED_DIM 64
#define N_NODES   150000
#define N_EDGES   2400000
#define N_BUCKETS 586       // ceil(150000/256), 256 rows per bucket
#define BCAP      4608      // static per-bucket window (ints)
#define PART_BLOCKS 256
#define MAX_BLK_EDGES 9376  // ceil(600000/256)*4

// ws layout (byte offsets), total 51,013,760 <= proven 51,033,344:
#define OFF_BCNT  0         // int32 x 586 (zeroed per launch)
#define OFF_BE    8192      // int2 x N {beg,end}            (ends 1,208,192; 128-aligned)
#define OFF_PS    1808256   // int32 x 586*4608 (128-aligned; ends 12,609,408)
#define OFF_XA    12611584  // bf16 x (N+1)*64 = 19,200,128  (4096-aligned; ends 31,811,712)
#define OFF_XB    31813632  // bf16 x (N+1)*64               (4096-aligned; ends 51,013,760)

__device__ __forceinline__ unsigned f2bf(float f) {  // RNE fp32 -> bf16 (as u16)
    unsigned u = __float_as_uint(f);
    return (u + 0x7fffu + ((u >> 16) & 1u)) >> 16;
}
__device__ __forceinline__ float bflo(unsigned u) { return __uint_as_float(u << 16); }
__device__ __forceinline__ float bfhi(unsigned u) { return __uint_as_float(u & 0xffff0000u); }
__device__ __forceinline__ float2 bf2(unsigned u) {  // bf16 pair -> float2
    float2 r; r.x = bflo(u); r.y = bfhi(u); return r;
}

// Pass 1: partition into static bucket windows, LDS-staged for coalesced
// writes. pack = (row&255)<<18 | col. Block 0 zeroes the dummy rows.
__global__ void partition_kernel(const int4* __restrict__ row4, const int4* __restrict__ col4,
                                 int* __restrict__ bcnt, unsigned* __restrict__ ps,
                                 uint2* __restrict__ yA, uint2* __restrict__ yB) {
    __shared__ int scanws[1024];                 // scan workspace (padded hist)
    __shared__ int lsize[N_BUCKETS];             // per-bucket count in this block
    __shared__ int lstart[N_BUCKETS + 1];        // exclusive starts in staged[]
    __shared__ int gbase[N_BUCKETS];             // reserved global bases
    __shared__ int lcur[N_BUCKETS];              // scatter cursors
    __shared__ unsigned staged[MAX_BLK_EDGES];   // bucket-sorted packed edges
    if (blockIdx.x == 0 && threadIdx.x < 16) {   // dummy row N_NODES of both tables
        uint2 z; z.x = 0u; z.y = 0u;
        yA[2400000 + threadIdx.x] = z;
        yB[2400000 + threadIdx.x] = z;
    }
    scanws[threadIdx.x] = 0;
    __syncthreads();
    const int total4 = N_EDGES / 4;
    int per4 = (total4 + gridDim.x - 1) / gridDim.x;
    int s4 = blockIdx.x * per4;
    int e4 = s4 + per4; if (e4 > total4) e4 = total4;
    const int cntE = (e4 - s4) * 4;
    // 1) histogram
    for (int i = s4 + (int)threadIdx.x; i < e4; i += (int)blockDim.x) {
        int4 r = row4[i];
        atomicAdd(&scanws[r.x >> 8], 1);
        atomicAdd(&scanws[r.y >> 8], 1);
        atomicAdd(&scanws[r.z >> 8], 1);
        atomicAdd(&scanws[r.w >> 8], 1);
    }
    __syncthreads();
    int myv = scanws[threadIdx.x];               // padded: 0 for t >= N_BUCKETS
    if (threadIdx.x < N_BUCKETS) lsize[threadIdx.x] = myv;
    __syncthreads();
    // 2) Hillis-Steele inclusive scan over 1024 (covers 586)
    for (int off = 1; off < 1024; off <<= 1) {
        int t = (threadIdx.x >= off) ? scanws[threadIdx.x - off] : 0;
        __syncthreads();
        scanws[threadIdx.x] += t;
        __syncthreads();
    }
    if (threadIdx.x < N_BUCKETS) {
        int incl = scanws[threadIdx.x];
        int st = incl - lsize[threadIdx.x];
        lstart[threadIdx.x] = st;
        lcur[threadIdx.x] = st;
        int c = lsize[threadIdx.x];
        gbase[threadIdx.x] = c ? (threadIdx.x * BCAP + atomicAdd(&bcnt[threadIdx.x], c)) : 0;
    }
    if (threadIdx.x == 0) lstart[N_BUCKETS] = cntE;
    __syncthreads();
    // 3) scatter into bucket-sorted LDS
    for (int i = s4 + (int)threadIdx.x; i < e4; i += (int)blockDim.x) {
        int4 r = row4[i];
        int4 c = col4[i];
        int pos;
        pos = atomicAdd(&lcur[r.x >> 8], 1); staged[pos] = ((unsigned)(r.x & 255) << 18) | (unsigned)c.x;
        pos = atomicAdd(&lcur[r.y >> 8], 1); staged[pos] = ((unsigned)(r.y & 255) << 18) | (unsigned)c.y;
        pos = atomicAdd(&lcur[r.z >> 8], 1); staged[pos] = ((unsigned)(r.z & 255) << 18) | (unsigned)c.z;
        pos = atomicAdd(&lcur[r.w >> 8], 1); staged[pos] = ((unsigned)(r.w & 255) << 18) | (unsigned)c.w;
    }
    __syncthreads();
    // 4) sequential writeback: consecutive i -> consecutive dest within runs
    for (int i = (int)threadIdx.x; i < cntE; i += (int)blockDim.x) {
        int lo = 0, hi = N_BUCKETS - 1;          // largest b with lstart[b] <= i
        while (lo < hi) {
            int mid = (lo + hi + 1) >> 1;
            if (lstart[mid] <= i) lo = mid; else hi = mid - 1;
        }
        ps[gbase[lo] + (i - lstart[lo])] = staged[i];
    }
}

// Pass 2: one block (512 thr) per bucket. Stage bucket edges in LDS, build
// 256-row hist, even-padded row starts, be, row-sort into LDS lsort,
// SEQUENTIAL coalesced ps writeback, and y0 = x0*rsqrt(deg) rows.
__global__ void fine_kernel(const int* __restrict__ bcnt, int* __restrict__ ps,
                            int2* __restrict__ be,
                            const float4* __restrict__ user, const float4* __restrict__ item,
                            uint2* __restrict__ yA) {
    __shared__ int ledge[BCAP];
    __shared__ int lsort[BCAP];
    __shared__ int rh[256];
    __shared__ int rsc[256];
    __shared__ int rcur[256];
    __shared__ float rq[256];
    int b = blockIdx.x;
    int base = b * BCAP;
    int cnt  = bcnt[b];
    if (cnt > BCAP) cnt = BCAP;          // defensive (never expected)
    if (threadIdx.x < 256) rh[threadIdx.x] = 0;
    __syncthreads();
    for (int i = threadIdx.x; i < cnt; i += blockDim.x) {
        int p = ps[base + i];
        ledge[i] = p;
        atomicAdd(&rh[p >> 18], 1);
    }
    __syncthreads();
    if (threadIdx.x < 256) rsc[threadIdx.x] = (rh[threadIdx.x] + 1) & ~1;  // even row size
    __syncthreads();
    for (int off = 1; off < 256; off <<= 1) {
        int t = (threadIdx.x < 256 && threadIdx.x >= off) ? rsc[threadIdx.x - off] : 0;
        __syncthreads();
        if (threadIdx.x < 256) rsc[threadIdx.x] += t;
        __syncthreads();
    }
    if (threadIdx.x < 256) {
        int r = threadIdx.x;
        int sz = (rh[r] + 1) & ~1;
        int pstart = rsc[r] - sz;            // even (base even, sizes even)
        rcur[r] = pstart;
        int n = (b << 8) + r;
        if (n < N_NODES) {
            int2 p; p.x = base + pstart; p.y = base + pstart + rh[r];
            be[n] = p;
            float d = (float)(rh[r] < 1 ? 1 : rh[r]);
            rq[r] = rsqrtf(d);
        }
    }
    __syncthreads();
    // row-sort scatter into LDS (int LDS atomics + LDS writes only)
    for (int i = threadIdx.x; i < cnt; i += blockDim.x) {
        int p = ledge[i];
        int pos = atomicAdd(&rcur[p >> 18], 1);      // LDS atomic
        lsort[pos] = p & 0x3FFFF;                    // sorted col, row bits stripped
    }
    __syncthreads();
    // sequential coalesced writeback of the padded layout (pads = garbage,
    // discarded by pull predicates before address formation)
    int tot = rsc[255];                              // padded total
    if (tot > BCAP) tot = BCAP;                      // defensive
    for (int i = threadIdx.x; i < tot; i += blockDim.x)
        ps[base + i] = lsort[i];
    // y0 rows for this bucket: 256 rows x 16 uint2 words; word w covers float4 w.
    for (int idx = threadIdx.x; idx < 4096; idx += blockDim.x) {
        int r = idx >> 4, w = idx & 15;
        int n = (b << 8) + r;
        if (n < N_NODES) {
            const float4* src = (n < NUM_USERS) ? (user + (size_t)n * 16)
                                                : (item + (size_t)(n - NUM_USERS) * 16);
            float4 v = src[w];
            float rn = rq[r];
            uint2 o;
            o.x = f2bf(v.x * rn) | (f2bf(v.y * rn) << 16);
            o.y = f2bf(v.z * rn) | (f2bf(v.w * rn) << 16);
            yA[(size_t)n * 16 + w] = o;
        }
    }
}

// 8 lanes per node, 8 nodes per wave (identity order: consecutive nodes ->
// contiguous scol runs + contiguous stores; R21/R25 lesson: ANY reorder
// loses). Lane q owns dims [8q,8q+8); 8-edge unroll: 4 int2 scol + 8 uint4
// gathers in flight. OOB -> dummy zero row N_NODES, predicated BEFORE
// addressing. Over-read <=24B past ps end lands in the slack before XA.
__device__ __forceinline__ void pull_sum(int2 bnd, int q,
                                         const int2* __restrict__ scol2,
                                         const uint4* __restrict__ xin, float2 sum[4]) {
    int endj = bnd.y;
    for (int j = bnd.x; j < endj; j += 8) {
        int h = j >> 1;
        int2 cc0 = scol2[h];
        int2 cc1 = scol2[h + 1];
        int2 cc2 = scol2[h + 2];
        int2 cc3 = scol2[h + 3];
        int c0 = cc0.x;                               // j < endj by loop cond
        int c1 = (j + 1 < endj) ? cc0.y : N_NODES;
        int c2 = (j + 2 < endj) ? cc1.x : N_NODES;
        int c3 = (j + 3 < endj) ? cc1.y : N_NODES;
        int c4 = (j + 4 < endj) ? cc2.x : N_NODES;
        int c5 = (j + 5 < endj) ? cc2.y : N_NODES;
        int c6 = (j + 6 < endj) ? cc3.x : N_NODES;
        int c7 = (j + 7 < endj) ? cc3.y : N_NODES;
        uint4 X0 = xin[(size_t)c0 * 8 + q];
        uint4 X1 = xin[(size_t)c1 * 8 + q];
        uint4 X2 = xin[(size_t)c2 * 8 + q];
        uint4 X3 = xin[(size_t)c3 * 8 + q];
        uint4 X4 = xin[(size_t)c4 * 8 + q];
        uint4 X5 = xin[(size_t)c5 * 8 + q];
        uint4 X6 = xin[(size_t)c6 * 8 + q];
        uint4 X7 = xin[(size_t)c7 * 8 + q];
        sum[0] += (bf2(X0.x) + bf2(X1.x)) + (bf2(X2.x) + bf2(X3.x))
                + (bf2(X4.x) + bf2(X5.x)) + (bf2(X6.x) + bf2(X7.x));
        sum[1] += (bf2(X0.y) + bf2(X1.y)) + (bf2(X2.y) + bf2(X3.y))
                + (bf2(X4.y) + bf2(X5.y)) + (bf2(X6.y) + bf2(X7.y));
        sum[2] += (bf2(X0.z) + bf2(X1.z)) + (bf2(X2.z) + bf2(X3.z))
                + (bf2(X4.z) + bf2(X5.z)) + (bf2(X6.z) + bf2(X7.z));
        sum[3] += (bf2(X0.w) + bf2(X1.w)) + (bf2(X2.w) + bf2(X3.w))
                + (bf2(X4.w) + bf2(X5.w)) + (bf2(X6.w) + bf2(X7.w));
    }
}

// Middle layers: y_{l+1}[n] = rsqrt(deg)^2 * sum  (bf16). All 64 lanes store.
__global__ void pull_kernel(const int2* __restrict__ be,
                            const int2* __restrict__ scol2,
                            const uint4* __restrict__ xin, uint4* __restrict__ xout) {
    int t = blockIdx.x * blockDim.x + (int)threadIdx.x;
    int n = t >> 3;
    if (n >= N_NODES) return;
    int q = t & 7;
    int2 bnd = be[n];
    float2 sum[4];
    sum[0] = make_float2(0.f, 0.f); sum[1] = make_float2(0.f, 0.f);
    sum[2] = make_float2(0.f, 0.f); sum[3] = make_float2(0.f, 0.f);
    pull_sum(bnd, q, scol2, xin, sum);
    int deg = bnd.y - bnd.x;
    float d = (float)(deg < 1 ? 1 : deg);
    float rn = rsqrtf(d);
    float s2 = rn * rn;
    uint4 p;
    p.x = f2bf(sum[0].x * s2) | (f2bf(sum[0].y * s2) << 16);
    p.y = f2bf(sum[1].x * s2) | (f2bf(sum[1].y * s2) << 16);
    p.z = f2bf(sum[2].x * s2) | (f2bf(sum[2].y * s2) << 16);
    p.w = f2bf(sum[3].x * s2) | (f2bf(sum[3].y * s2) << 16);
    xout[(size_t)n * 8 + q] = p;
}

// Last layer: acc = (x0 + (y1+y2)*sd + rn*sum) / 4, rn = rsqrt(deg), sd = sqrt(deg).
__global__ void pull_last_kernel(const int2* __restrict__ be,
                                 const int2* __restrict__ scol2,
                                 const uint4* __restrict__ xin,   // y2 (gather table)
                                 const uint4* __restrict__ xprev, // y1
                                 const float4* __restrict__ user, const float4* __restrict__ item,
                                 float4* __restrict__ acc4) {
    int t = blockIdx.x * blockDim.x + (int)threadIdx.x;
    int n = t >> 3;
    if (n >= N_NODES) return;
    int q = t & 7;
    int2 bnd = be[n];
    float2 sum[4];
    sum[0] = make_float2(0.f, 0.f); sum[1] = make_float2(0.f, 0.f);
    sum[2] = make_float2(0.f, 0.f); sum[3] = make_float2(0.f, 0.f);
    pull_sum(bnd, q, scol2, xin, sum);
    int deg = bnd.y - bnd.x;
    float d = (float)(deg < 1 ? 1 : deg);
    float rn = rsqrtf(d);
    float sd = sqrtf(d);
    uint4 p2 = xin  [(size_t)n * 8 + q];
    uint4 p1 = xprev[(size_t)n * 8 + q];
    const float4* x0 = (n < NUM_USERS) ? (user + (size_t)n * 16)
                                       : (item + (size_t)(n - NUM_USERS) * 16);
    float4 a0 = x0[q * 2], a1 = x0[q * 2 + 1];
    float4 o0, o1;
    o0.x = (a0.x + (bflo(p1.x) + bflo(p2.x)) * sd + rn * sum[0].x) * 0.25f;
    o0.y = (a0.y + (bfhi(p1.x) + bfhi(p2.x)) * sd + rn * sum[0].y) * 0.25f;
    o0.z = (a0.z + (bflo(p1.y) + bflo(p2.y)) * sd + rn * sum[1].x) * 0.25f;
    o0.w = (a0.w + (bfhi(p1.y) + bfhi(p2.y)) * sd + rn * sum[1].y) * 0.25f;
    o1.x = (a1.x + (bflo(p1.z) + bflo(p2.z)) * sd + rn * sum[2].x) * 0.25f;
    o1.y = (a1.y + (bfhi(p1.z) + bfhi(p2.z)) * sd + rn * sum[2].y) * 0.25f;
    o1.z = (a1.z + (bflo(p1.w) + bflo(p2.w)) * sd + rn * sum[3].x) * 0.25f;
    o1.w = (a1.w + (bfhi(p1.w) + bfhi(p2.w)) * sd + rn * sum[3].y) * 0.25f;
    size_t o4 = (size_t)n * 16 + q * 2;
    acc4[o4] = o0;
    acc4[o4 + 1] = o1;
}

extern "C" void kernel_launch(void* const* d_in, const int* in_sizes, int n_in,
                              void* d_out, int out_size, void* d_ws, size_t ws_size,
                              hipStream_t stream) {
    const float* user = (const float*)d_in[0];
    const float* item = (const float*)d_in[1];
    const int*   ei   = (const int*)d_in[2];
    const int* row = ei;            // edge_index[0]
    const int* col = ei + N_EDGES;  // edge_index[1]

    char*  ws   = (char*)d_ws;
    int*   bcnt = (int*)(ws + OFF_BCNT);
    int2*  be   = (int2*)(ws + OFF_BE);
    int*   ps   = (int*)(ws + OFF_PS);
    char*  xA   = ws + OFF_XA;   // bf16 y-tables, (N+1) rows (row N = zeros)
    char*  xB   = ws + OFF_XB;
    float* acc  = (float*)d_out;

    // CSR build: LDS-staged partition -> fine (LDS sort + coalesced writeback)
    hipMemsetAsync(bcnt, 0, 4096, stream);
    partition_kernel<<<PART_BLOCKS, 1024, 0, stream>>>((const int4*)row, (const int4*)col,
                                                       bcnt, (unsigned*)ps,
                                                       (uint2*)xA, (uint2*)xB);
    fine_kernel<<<N_BUCKETS, 512, 0, stream>>>(bcnt, ps, be,
                                               (const float4*)user, (const float4*)item,
                                               (uint2*)xA);

    // 3 pull layers: 8 threads per node, identity node order
    const int grid = (N_NODES * 8 + 255) / 256;
    pull_kernel<<<grid, 256, 0, stream>>>(be, (const int2*)ps,
        (const uint4*)xA, (uint4*)xB);
    pull_kernel<<<grid, 256, 0, stream>>>(be, (const int2*)ps,
        (const uint4*)xB, (uint4*)xA);
    pull_last_kernel<<<grid, 256, 0, stream>>>(be, (const int2*)ps,
        (const uint4*)xA, (const uint4*)xB,
        (const float4*)user, (const float4*)item, (float4*)acc);
}